// Round 4
// baseline (225.257 us; speedup 1.0000x reference)
//
#include <hip/hip_runtime.h>

#define Bq 64
#define Sq 512
#define Hq 768
#define Tq 16
#define Vq 30522
#define EMP 516   // emT row stride (pad: 2-way banks = free)
#define WLP 20    // W LDS row stride (pad: 2-way banks = free)

typedef unsigned int u32;
typedef unsigned long long u64;

// ---------- cross-lane helpers ----------
__device__ __forceinline__ float bperm_f(float v, int byteidx) {
    return __int_as_float(__builtin_amdgcn_ds_bpermute(byteidx, __float_as_int(v)));
}
template <int CTRL>
__device__ __forceinline__ int dpp_i(int v) {
    return __builtin_amdgcn_mov_dpp(v, CTRL, 0xF, 0xF, true);
}
template <int CTRL>
__device__ __forceinline__ u32 dpp_u(u32 v) { return (u32)dpp_i<CTRL>((int)v); }
template <int CTRL>
__device__ __forceinline__ float dpp_f(float v) {
    return __int_as_float(dpp_i<CTRL>(__float_as_int(v)));
}

#define QX1 0xB1
#define QX2 0x4E
#define RR4  0x124
#define RR8  0x128
#define RR12 0x12C

#if defined(__gfx950__) && __has_builtin(__builtin_amdgcn_permlane32_swap) && __has_builtin(__builtin_amdgcn_permlane16_swap)
#define HAVE_PL 1
#else
#define HAVE_PL 0
#endif

#if HAVE_PL
__device__ __forceinline__ u32 xlane32(u32 x) {
    auto r = __builtin_amdgcn_permlane32_swap((int)x, (int)x, false, false);
    return ((u32)r[0]) ^ ((u32)r[1]) ^ x;
}
__device__ __forceinline__ u32 xlane16(u32 x) {
    auto r = __builtin_amdgcn_permlane16_swap((int)x, (int)x, false, false);
    return ((u32)r[0]) ^ ((u32)r[1]) ^ x;
}
__device__ __forceinline__ void gather4(u32 x, bool swA, bool swB,
                                        u32& q0, u32& q1, u32& q2, u32& q3) {
    u32 t  = xlane32(x);
    u32 y  = dpp_u<QX2>(t);
    u32 z  = swA ? y : x;
    u32 t2 = xlane16(z);
    u32 y2 = dpp_u<QX1>(t2);
    q0 = swB ? y2 : z;
    q1 = dpp_u<RR4>(q0);
    q2 = dpp_u<RR8>(q0);
    q3 = dpp_u<RR12>(q0);
}
#endif

__device__ __forceinline__ u32 packnib(u32 d) {
    u32 y = d | (d >> 4);
    y &= 0x00FF00FFu;
    y = (y | (y >> 8)) & 0xFFFFu;
    return y;
}
__device__ __forceinline__ u32 nib64(u64 f, u32 s) {
    return ((u32)(f >> (s << 2))) & 15u;
}

// ---------- K0: table_logits = emb @ W + b.  4 lanes per vocab row, W in LDS ----------
__global__ __launch_bounds__(256) void k_table(const float* __restrict__ emb,
                                               const float* __restrict__ W,
                                               const float* __restrict__ bias,
                                               float* __restrict__ table,
                                               float* __restrict__ out) {
    if (blockIdx.x == 0 && threadIdx.x == 0) out[1] = 0.0f;
    __shared__ float WL[Hq * WLP];   // 60 KB, rows padded to 20 floats
    const int tid = threadIdx.x;

    // stage W: 3072 float4 over 256 threads
    #pragma unroll
    for (int k = 0; k < 12; ++k) {
        int idx = tid + (k << 8);        // float4 slot 0..3071
        int h = idx >> 2;
        int c = idx & 3;
        float4 v = *reinterpret_cast<const float4*>(W + idx * 4);
        *reinterpret_cast<float4*>(&WL[h * WLP + (c << 2)]) = v;
    }
    __syncthreads();

    const int r_loc = tid >> 2;          // 0..63
    const int q     = tid & 3;           // h-quad group
    const int v     = blockIdx.x * 64 + r_loc;
    const int vc    = v < Vq ? v : Vq - 1;
    const float* arow = emb + (size_t)vc * Hq;

    float acc[16];
    #pragma unroll
    for (int t = 0; t < 16; ++t) acc[t] = 0.0f;

    // lane's n-th float4: h_base = n*16 + q*4, n = 0..47
    float4 buf[8];
    #pragma unroll
    for (int i = 0; i < 8; ++i)
        buf[i] = *reinterpret_cast<const float4*>(arow + i * 16 + q * 4);

    for (int c = 0; c < 6; ++c) {
        float4 nxt[8];
        const bool more = c < 5;
        if (more) {
            #pragma unroll
            for (int i = 0; i < 8; ++i)
                nxt[i] = *reinterpret_cast<const float4*>(arow + ((c + 1) * 8 + i) * 16 + q * 4);
        }
        #pragma unroll
        for (int i = 0; i < 8; ++i) {
            const int hb = (c * 8 + i) * 16 + q * 4;
            #pragma unroll
            for (int a = 0; a < 4; ++a) {
                float av = (a == 0) ? buf[i].x : (a == 1) ? buf[i].y : (a == 2) ? buf[i].z : buf[i].w;
                const float* wr = &WL[(hb + a) * WLP];
                float4 w0 = *reinterpret_cast<const float4*>(wr);
                float4 w1 = *reinterpret_cast<const float4*>(wr + 4);
                float4 w2 = *reinterpret_cast<const float4*>(wr + 8);
                float4 w3 = *reinterpret_cast<const float4*>(wr + 12);
                acc[0]  = fmaf(av, w0.x, acc[0]);
                acc[1]  = fmaf(av, w0.y, acc[1]);
                acc[2]  = fmaf(av, w0.z, acc[2]);
                acc[3]  = fmaf(av, w0.w, acc[3]);
                acc[4]  = fmaf(av, w1.x, acc[4]);
                acc[5]  = fmaf(av, w1.y, acc[5]);
                acc[6]  = fmaf(av, w1.z, acc[6]);
                acc[7]  = fmaf(av, w1.w, acc[7]);
                acc[8]  = fmaf(av, w2.x, acc[8]);
                acc[9]  = fmaf(av, w2.y, acc[9]);
                acc[10] = fmaf(av, w2.z, acc[10]);
                acc[11] = fmaf(av, w2.w, acc[11]);
                acc[12] = fmaf(av, w3.x, acc[12]);
                acc[13] = fmaf(av, w3.y, acc[13]);
                acc[14] = fmaf(av, w3.z, acc[14]);
                acc[15] = fmaf(av, w3.w, acc[15]);
            }
        }
        if (more) {
            #pragma unroll
            for (int i = 0; i < 8; ++i) buf[i] = nxt[i];
        }
    }
    // quad-reduce all 16 accumulators (sum over the 4 h-groups)
    #pragma unroll
    for (int t = 0; t < 16; ++t) {
        acc[t] += dpp_f<QX1>(acc[t]);
        acc[t] += dpp_f<QX2>(acc[t]);
    }
    if (v < Vq) {
        float4 bv = *reinterpret_cast<const float4*>(bias + q * 4);
        float4 o = make_float4(acc[q * 4] + bv.x, acc[q * 4 + 1] + bv.y,
                               acc[q * 4 + 2] + bv.z, acc[q * 4 + 3] + bv.w);
        *reinterpret_cast<float4*>(table + (size_t)v * Tq + q * 4) = o;
    }
}

// ---------- K1: fused CRF scans. grid=128, block=64 (1 wave). ----------
// blocks 0..63: denominator + numerator.  blocks 64..127: viterbi + outputs.
__global__ __launch_bounds__(64) void k_scan(const int* __restrict__ src,
                                             const int* __restrict__ label,
                                             const int* __restrict__ pmask,
                                             const float* __restrict__ table,
                                             const float* __restrict__ start_t,
                                             const float* __restrict__ end_t,
                                             const float* __restrict__ trans,
                                             float* __restrict__ nd,
                                             float* __restrict__ out) {
    __shared__ __align__(16) float emT[Tq * EMP];     // transposed: emT[j][t] (den: FF values)
    __shared__ __align__(16) unsigned char hist8[Sq * Tq];
    __shared__ int srcl[Sq];
    __shared__ int labl[Sq];
    __shared__ __align__(8) unsigned char predi8[Sq];

    const int lane = threadIdx.x;
    const int b = blockIdx.x & 63;
    const bool vit = blockIdx.x >= 64;

    #pragma unroll
    for (int k = 0; k < 8; ++k) {
        int t = lane + (k << 6);
        srcl[t] = src[b * Sq + t];
        labl[t] = label[b * Sq + t];
    }
    __syncthreads();
    // gather emissions transposed; den path stores FF = exp(em)/16 directly
    if (!vit) {
        #pragma unroll 4
        for (int k = 0; k < 128; ++k) {
            int idx = lane + (k << 6);
            int t = idx >> 4, jj = idx & 15;
            emT[jj * EMP + t] = __expf(table[(size_t)srcl[t] * Tq + jj]) * 0.0625f;
        }
    } else {
        #pragma unroll 4
        for (int k = 0; k < 128; ++k) {
            int idx = lane + (k << 6);
            int t = idx >> 4, jj = idx & 15;
            emT[jj * EMP + t] = table[(size_t)srcl[t] * Tq + jj];
        }
    }
    __syncthreads();

    const int j = lane >> 2;
    const int g = lane & 3;
    const float4* emrow = reinterpret_cast<const float4*>(&emT[j * EMP]);

    // probe the permlane gather network; fall back to bpermute if wrong
    const bool swA = (((lane >> 5) ^ (lane >> 1)) & 1) != 0;
    const bool swB = (((lane >> 4) ^ lane) & 1) != 0;
    int k0 = 0, k1 = 1, k2 = 2, k3 = 3;
    bool fastok = false;
#if HAVE_PL
    {
        u32 q0, q1, q2, q3;
        gather4((u32)j, swA, swB, q0, q1, q2, q3);
        bool ok = ((q0 >> 2) == (u32)g) && ((q1 >> 2) == (u32)g) &&
                  ((q2 >> 2) == (u32)g) && ((q3 >> 2) == (u32)g);
        u32 cov = (1u << (q0 & 3)) | (1u << (q1 & 3)) | (1u << (q2 & 3)) | (1u << (q3 & 3));
        ok = ok && (cov == 15u);
        fastok = (__all(ok ? 1 : 0) != 0);
        if (fastok) { k0 = (int)(q0 & 3); k1 = (int)(q1 & 3); k2 = (int)(q2 & 3); k3 = (int)(q3 & 3); }
    }
#endif
    const int bidx0 = (g << 6), bidx1 = (g << 6) + 16, bidx2 = (g << 6) + 32, bidx3 = (g << 6) + 48;

    if (!vit) {
        // ================= denominator: linear-domain forward (FF precomputed) =================
        float E0 = __expf(trans[(4 * g + k0) * Tq + j]);
        float E1 = __expf(trans[(4 * g + k1) * Tq + j]);
        float E2 = __expf(trans[(4 * g + k2) * Tq + j]);
        float E3 = __expf(trans[(4 * g + k3) * Tq + j]);

        float4 f0 = emrow[0];
        float p = __expf(start_t[j]) * f0.x * 16.0f;   // exp(start + em0)

#define DEN_STEP_PL(ff)  { u32 qa, qb, qc, qd;                                         \
            gather4(__float_as_uint(p), swA, swB, qa, qb, qc, qd);                     \
            float s = (__uint_as_float(qa) * E0 + __uint_as_float(qb) * E1)            \
                    + (__uint_as_float(qc) * E2 + __uint_as_float(qd) * E3);           \
            s += dpp_f<QX1>(s);  s += dpp_f<QX2>(s);  p = s * (ff); }
#define DEN_STEP_BP(ff)  { float p0 = bperm_f(p, bidx0), p1 = bperm_f(p, bidx1),       \
                                 p2 = bperm_f(p, bidx2), p3 = bperm_f(p, bidx3);       \
            float s = (p0 * E0 + p1 * E1) + (p2 * E2 + p3 * E3);                       \
            s += dpp_f<QX1>(s);  s += dpp_f<QX2>(s);  p = s * (ff); }

#if HAVE_PL
        if (fastok) {
            DEN_STEP_PL(f0.y) DEN_STEP_PL(f0.z) DEN_STEP_PL(f0.w)
            float4 fc = emrow[1];
            for (int t0 = 4; t0 < Sq; t0 += 4) {
                float4 fn;
                if (t0 + 4 < Sq) fn = emrow[(t0 >> 2) + 1];
                DEN_STEP_PL(fc.x) DEN_STEP_PL(fc.y) DEN_STEP_PL(fc.z) DEN_STEP_PL(fc.w)
                fc = fn;
            }
        } else
#endif
        {
            DEN_STEP_BP(f0.y) DEN_STEP_BP(f0.z) DEN_STEP_BP(f0.w)
            float4 fc = emrow[1];
            for (int t0 = 4; t0 < Sq; t0 += 4) {
                float4 fn;
                if (t0 + 4 < Sq) fn = emrow[(t0 >> 2) + 1];
                DEN_STEP_BP(fc.x) DEN_STEP_BP(fc.y) DEN_STEP_BP(fc.z) DEN_STEP_BP(fc.w)
                fc = fn;
            }
        }
        float val = p * __expf(end_t[j]);
        #pragma unroll
        for (int off = 1; off < 64; off <<= 1) val += __shfl_xor(val, off);
        float den = (float)(511.0 * 2.7725887222397811) + __logf(val * 0.25f);

        // ================= numerator (raw logits from global table) =================
        float numv = 0.0f;
        int sl = 0;
        #pragma unroll
        for (int k = 0; k < 8; ++k) {
            int t = lane + (k << 6);
            int tag = labl[t];
            int m = pmask[b * Sq + t];
            sl += m;
            float emtt = table[(size_t)srcl[t] * Tq + tag];
            if (t == 0) {
                numv += start_t[tag] + emtt;
            } else {
                int tp = labl[t - 1];
                numv += (float)m * (trans[tp * Tq + tag] + emtt);
            }
        }
        #pragma unroll
        for (int off = 1; off < 64; off <<= 1) {
            numv += __shfl_xor(numv, off);
            sl += __shfl_xor(sl, off);
        }
        if (lane == 0) {
            int last = labl[sl - 1];
            nd[b] = (numv + end_t[last]) - den;
        }
    } else {
        // ================= viterbi forward =================
        float T0 = trans[(4 * g + k0) * Tq + j];
        float T1 = trans[(4 * g + k1) * Tq + j];
        float T2 = trans[(4 * g + k2) * Tq + j];
        float T3 = trans[(4 * g + k3) * Tq + j];
        const int i0 = 4 * g + k0, i1 = 4 * g + k1, i2 = 4 * g + k2, i3 = 4 * g + k3;

#define VIT_STEP_PL(emv, th) { u32 qa, qb, qc, qd;                                     \
            gather4(__float_as_uint(sc), swA, swB, qa, qb, qc, qd);                    \
            float v0 = __uint_as_float(qa) + T0, v1 = __uint_as_float(qb) + T1;        \
            float v2 = __uint_as_float(qc) + T2, v3 = __uint_as_float(qd) + T3;        \
            float ml = fmaxf(fmaxf(v0, v1), fmaxf(v2, v3));                            \
            float m1 = fmaxf(ml, dpp_f<QX1>(ml));                                      \
            float mv = fmaxf(m1, dpp_f<QX2>(m1));                                      \
            sc = mv + (emv);                                                           \
            int c0 = (v0 == mv) ? i0 : 99, c1 = (v1 == mv) ? i1 : 99;                  \
            int c2 = (v2 == mv) ? i2 : 99, c3 = (v3 == mv) ? i3 : 99;                  \
            int li = min(min(c0, c1), min(c2, c3));                                    \
            li = min(li, dpp_i<QX1>(li));  li = min(li, dpp_i<QX2>(li));               \
            if (g == 0) hist8[(th) * Tq + j] = (unsigned char)li; }
#define VIT_STEP_BP(emv, th) { float v0 = bperm_f(sc, bidx0) + T0,                     \
                 v1 = bperm_f(sc, bidx1) + T1, v2 = bperm_f(sc, bidx2) + T2,           \
                 v3 = bperm_f(sc, bidx3) + T3;                                         \
            float ml = fmaxf(fmaxf(v0, v1), fmaxf(v2, v3));                            \
            float m1 = fmaxf(ml, dpp_f<QX1>(ml));                                      \
            float mv = fmaxf(m1, dpp_f<QX2>(m1));                                      \
            sc = mv + (emv);                                                           \
            int c0 = (v0 == mv) ? i0 : 99, c1 = (v1 == mv) ? i1 : 99;                  \
            int c2 = (v2 == mv) ? i2 : 99, c3 = (v3 == mv) ? i3 : 99;                  \
            int li = min(min(c0, c1), min(c2, c3));                                    \
            li = min(li, dpp_i<QX1>(li));  li = min(li, dpp_i<QX2>(li));               \
            if (g == 0) hist8[(th) * Tq + j] = (unsigned char)li; }

        float4 e0 = emrow[0];
        float sc = start_t[j] + e0.x;
#if HAVE_PL
        if (fastok) {
            VIT_STEP_PL(e0.y, 0) VIT_STEP_PL(e0.z, 1) VIT_STEP_PL(e0.w, 2)
            float4 fc = emrow[1];
            for (int t0 = 4; t0 < Sq; t0 += 4) {
                float4 fn;
                if (t0 + 4 < Sq) fn = emrow[(t0 >> 2) + 1];
                VIT_STEP_PL(fc.x, t0 - 1) VIT_STEP_PL(fc.y, t0)
                VIT_STEP_PL(fc.z, t0 + 1) VIT_STEP_PL(fc.w, t0 + 2)
                fc = fn;
            }
        } else
#endif
        {
            VIT_STEP_BP(e0.y, 0) VIT_STEP_BP(e0.z, 1) VIT_STEP_BP(e0.w, 2)
            float4 fc = emrow[1];
            for (int t0 = 4; t0 < Sq; t0 += 4) {
                float4 fn;
                if (t0 + 4 < Sq) fn = emrow[(t0 >> 2) + 1];
                VIT_STEP_BP(fc.x, t0 - 1) VIT_STEP_BP(fc.y, t0)
                VIT_STEP_BP(fc.z, t0 + 1) VIT_STEP_BP(fc.w, t0 + 2)
                fc = fn;
            }
        }
        // final argmax over states (ties -> lowest index)
        float fv = sc + end_t[j];
        int fi = j;
        #pragma unroll
        for (int off = 4; off < 64; off <<= 1) {
            float ov = __shfl_xor(fv, off);
            int oi = __shfl_xor(fi, off);
            bool take = (ov > fv) || (ov == fv && oi < fi);
            fv = take ? ov : fv;
            fi = take ? oi : fi;
        }
        if (lane < 16) hist8[511 * Tq + lane] = (unsigned char)lane;  // identity row
        __syncthreads();

        // ===== backtrack via exact function-composition scan =====
        u64 rp[8];
        #pragma unroll
        for (int k = 0; k < 8; ++k) {
            uint4 rw = *reinterpret_cast<const uint4*>(&hist8[(lane * 8 + k) * Tq]);
            u32 lo = packnib(rw.x) | (packnib(rw.y) << 16);
            u32 hi = packnib(rw.z) | (packnib(rw.w) << 16);
            rp[k] = (u64)lo | ((u64)hi << 32);
        }
        u64 F = rp[7];
        #pragma unroll
        for (int k = 6; k >= 0; --k) {
            u64 nf = 0;
            #pragma unroll
            for (int e = 0; e < 16; ++e) {
                u32 s = (u32)(F >> (e * 4)) & 15u;
                nf |= ((u64)nib64(rp[k], s)) << (e * 4);
            }
            F = nf;
        }
        u32 Flo = (u32)F, Fhi = (u32)(F >> 32);

        u32 pk[8] = {0, 0, 0, 0, 0, 0, 0, 0};
        u32 E = (u32)fi;
        #pragma unroll 64
        for (int c = 63; c >= 0; --c) {
            u64 Fc = ((u64)(u32)__builtin_amdgcn_readlane((int)Fhi, c) << 32)
                   | (u64)(u32)__builtin_amdgcn_readlane((int)Flo, c);
            pk[c >> 3] |= E << ((c & 7) * 4);
            E = nib64(Fc, E);
        }

        u32 a0 = (lane & 8) ? pk[1] : pk[0];
        u32 a1 = (lane & 8) ? pk[3] : pk[2];
        u32 a2 = (lane & 8) ? pk[5] : pk[4];
        u32 a3 = (lane & 8) ? pk[7] : pk[6];
        u32 b0 = (lane & 16) ? a1 : a0;
        u32 b1 = (lane & 16) ? a3 : a2;
        u32 c0s = (lane & 32) ? b1 : b0;
        u32 cur = (c0s >> ((lane & 7) * 4)) & 15u;
        u32 w0 = 0, w1 = 0;
        #pragma unroll
        for (int k = 7; k >= 0; --k) {
            cur = nib64(rp[k], cur);
            if (k >= 4) w1 |= cur << ((k - 4) * 8);
            else        w0 |= cur << (k * 8);
        }
        *reinterpret_cast<uint2*>(&predi8[lane * 8]) = make_uint2(w0, w1);
        __syncthreads();

        // ================= outputs =================
        int cnt = 0;
        #pragma unroll
        for (int k = 0; k < 8; ++k) {
            int s_ = lane + (k << 6);
            int lab = labl[s_];
            int pr = (int)predi8[s_];
            int mpr = lab > 0 ? pr : 0;
            out[2 + b * Sq + s_] = (float)mpr;
            out[2 + Bq * Sq + b * Sq + s_] = (float)lab;
            cnt += (mpr == lab) ? 1 : 0;
        }
        #pragma unroll
        for (int off = 1; off < 64; off <<= 1) cnt += __shfl_xor(cnt, off);
        if (lane == 0) atomicAdd(out + 1, (float)cnt);
    }
}

// ---------- K2: loss = -(sum_b nd[b]) / B ----------
__global__ __launch_bounds__(64) void k_final(const float* __restrict__ nd,
                                              float* __restrict__ out) {
    float v = nd[threadIdx.x];
    #pragma unroll
    for (int off = 1; off < 64; off <<= 1) v += __shfl_xor(v, off);
    if (threadIdx.x == 0) out[0] = -v * (1.0f / (float)Bq);
}

extern "C" void kernel_launch(void* const* d_in, const int* in_sizes, int n_in,
                              void* d_out, int out_size, void* d_ws, size_t ws_size,
                              hipStream_t stream) {
    const int*   src   = (const int*)d_in[0];
    const int*   label = (const int*)d_in[1];
    const int*   pmask = (const int*)d_in[2];
    const float* emb   = (const float*)d_in[3];
    const float* W     = (const float*)d_in[4];
    const float* bias  = (const float*)d_in[5];
    const float* st    = (const float*)d_in[6];
    const float* en    = (const float*)d_in[7];
    const float* tr    = (const float*)d_in[8];
    float* out = (float*)d_out;

    float* table = (float*)d_ws;
    float* nd    = table + (size_t)Vq * Tq;

    const int nblk = (Vq + 63) / 64;   // 477
    k_table<<<nblk, 256, 0, stream>>>(emb, W, bias, table, out);
    k_scan<<<128, 64, 0, stream>>>(src, label, pmask, table, st, en, tr, nd, out);
    k_final<<<1, 64, 0, stream>>>(nd, out);
}

// Round 5
// 109.207 us; speedup vs baseline: 2.0627x; 2.0627x over previous
//
#include <hip/hip_runtime.h>

#define Bq 64
#define Sq 512
#define Hq 768
#define Tq 16
#define Vq 30522
#define EMP 516   // emT row stride (pad: 2-way banks = free)
#define WLP 20    // W LDS row stride: 80B = 16B-aligned, 2-way banks = free

typedef unsigned int u32;
typedef unsigned long long u64;

// ---------- cross-lane helpers ----------
__device__ __forceinline__ float bperm_f(float v, int byteidx) {
    return __int_as_float(__builtin_amdgcn_ds_bpermute(byteidx, __float_as_int(v)));
}
template <int CTRL>
__device__ __forceinline__ int dpp_i(int v) {
    return __builtin_amdgcn_mov_dpp(v, CTRL, 0xF, 0xF, true);
}
template <int CTRL>
__device__ __forceinline__ u32 dpp_u(u32 v) { return (u32)dpp_i<CTRL>((int)v); }
template <int CTRL>
__device__ __forceinline__ float dpp_f(float v) {
    return __int_as_float(dpp_i<CTRL>(__float_as_int(v)));
}

#define QX1 0xB1
#define QX2 0x4E
#define RR4  0x124
#define RR8  0x128
#define RR12 0x12C

#if defined(__gfx950__) && __has_builtin(__builtin_amdgcn_permlane32_swap) && __has_builtin(__builtin_amdgcn_permlane16_swap)
#define HAVE_PL 1
#else
#define HAVE_PL 0
#endif

#if HAVE_PL
__device__ __forceinline__ u32 xlane32(u32 x) {
    auto r = __builtin_amdgcn_permlane32_swap((int)x, (int)x, false, false);
    return ((u32)r[0]) ^ ((u32)r[1]) ^ x;
}
__device__ __forceinline__ u32 xlane16(u32 x) {
    auto r = __builtin_amdgcn_permlane16_swap((int)x, (int)x, false, false);
    return ((u32)r[0]) ^ ((u32)r[1]) ^ x;
}
__device__ __forceinline__ void gather4(u32 x, bool swA, bool swB,
                                        u32& q0, u32& q1, u32& q2, u32& q3) {
    u32 t  = xlane32(x);
    u32 y  = dpp_u<QX2>(t);
    u32 z  = swA ? y : x;
    u32 t2 = xlane16(z);
    u32 y2 = dpp_u<QX1>(t2);
    q0 = swB ? y2 : z;
    q1 = dpp_u<RR4>(q0);
    q2 = dpp_u<RR8>(q0);
    q3 = dpp_u<RR12>(q0);
}
#endif

__device__ __forceinline__ u32 packnib(u32 d) {
    u32 y = d | (d >> 4);
    y &= 0x00FF00FFu;
    y = (y | (y >> 8)) & 0xFFFFu;
    return y;
}
__device__ __forceinline__ u32 nib64(u64 f, u32 s) {
    return ((u32)(f >> (s << 2))) & 15u;
}

// ---------- K0: table_logits = emb @ W + b ----------
// 256 threads, 64 rows/block (4 lanes per row, h split by quad). W in LDS (pad 20).
// Depth-8 static prefetch queue; __launch_bounds__(256,2) caps VGPR at 128 (no spill).
__global__ __launch_bounds__(256, 2) void k_table(const float* __restrict__ emb,
                                                  const float* __restrict__ W,
                                                  const float* __restrict__ bias,
                                                  float* __restrict__ table,
                                                  float* __restrict__ out) {
    if (blockIdx.x == 0 && threadIdx.x == 0) out[1] = 0.0f;
    __shared__ float WL[Hq * WLP];   // 60 KB
    const int tid = threadIdx.x;

    // stage W: 3072 float4 over 256 threads (coalesced 4KB/wave reads)
    #pragma unroll
    for (int k = 0; k < 12; ++k) {
        int idx = tid + (k << 8);          // flat float4 slot: h = idx>>2, c = idx&3
        float4 v = *reinterpret_cast<const float4*>(W + idx * 4);
        *reinterpret_cast<float4*>(&WL[(idx >> 2) * WLP + ((idx & 3) << 2)]) = v;
    }
    __syncthreads();

    const int r_loc = tid >> 2;            // row within block 0..63
    const int q     = tid & 3;             // h-quad group
    const int v     = blockIdx.x * 64 + r_loc;
    const int vc    = v < Vq ? v : Vq - 1;
    const float* arow = emb + (size_t)vc * Hq;

    float acc[16];
    #pragma unroll
    for (int t = 0; t < 16; ++t) acc[t] = 0.0f;

    // lane's float4 slots: n = q + 4k, k = 0..47
    float4 buf[8];
    #pragma unroll
    for (int u = 0; u < 8; ++u)
        buf[u] = *reinterpret_cast<const float4*>(arow + (q + 4 * u) * 4);

    for (int k6 = 0; k6 < 6; ++k6) {
        #pragma unroll
        for (int u = 0; u < 8; ++u) {
            const int k = k6 * 8 + u;
            float4 av = buf[u];
            if (k + 8 < 48)
                buf[u] = *reinterpret_cast<const float4*>(arow + (q + 4 * (k + 8)) * 4);
            const int hb = (q + 4 * k) * 4;      // first of 4 h values
            #pragma unroll
            for (int a = 0; a < 4; ++a) {
                float s = (a == 0) ? av.x : (a == 1) ? av.y : (a == 2) ? av.z : av.w;
                const float* wr = &WL[(hb + a) * WLP];
                float4 w0 = *reinterpret_cast<const float4*>(wr);
                float4 w1 = *reinterpret_cast<const float4*>(wr + 4);
                float4 w2 = *reinterpret_cast<const float4*>(wr + 8);
                float4 w3 = *reinterpret_cast<const float4*>(wr + 12);
                acc[0]  = fmaf(s, w0.x, acc[0]);
                acc[1]  = fmaf(s, w0.y, acc[1]);
                acc[2]  = fmaf(s, w0.z, acc[2]);
                acc[3]  = fmaf(s, w0.w, acc[3]);
                acc[4]  = fmaf(s, w1.x, acc[4]);
                acc[5]  = fmaf(s, w1.y, acc[5]);
                acc[6]  = fmaf(s, w1.z, acc[6]);
                acc[7]  = fmaf(s, w1.w, acc[7]);
                acc[8]  = fmaf(s, w2.x, acc[8]);
                acc[9]  = fmaf(s, w2.y, acc[9]);
                acc[10] = fmaf(s, w2.z, acc[10]);
                acc[11] = fmaf(s, w2.w, acc[11]);
                acc[12] = fmaf(s, w3.x, acc[12]);
                acc[13] = fmaf(s, w3.y, acc[13]);
                acc[14] = fmaf(s, w3.z, acc[14]);
                acc[15] = fmaf(s, w3.w, acc[15]);
            }
        }
    }
    // quad-reduce the 16 partial sums (sum over 4 h-groups)
    #pragma unroll
    for (int t = 0; t < 16; ++t) {
        acc[t] += dpp_f<QX1>(acc[t]);
        acc[t] += dpp_f<QX2>(acc[t]);
    }
    if (v < Vq) {
        float4 bv = *reinterpret_cast<const float4*>(bias + q * 4);
        float4 o = make_float4(acc[q * 4] + bv.x, acc[q * 4 + 1] + bv.y,
                               acc[q * 4 + 2] + bv.z, acc[q * 4 + 3] + bv.w);
        *reinterpret_cast<float4*>(table + (size_t)v * Tq + q * 4) = o;
    }
}

// ---------- K1: fused CRF scans. grid=128, block=64 (1 wave). ----------
// blocks 0..63: denominator + numerator.  blocks 64..127: viterbi + outputs.
__global__ __launch_bounds__(64) void k_scan(const int* __restrict__ src,
                                             const int* __restrict__ label,
                                             const int* __restrict__ pmask,
                                             const float* __restrict__ table,
                                             const float* __restrict__ start_t,
                                             const float* __restrict__ end_t,
                                             const float* __restrict__ trans,
                                             float* __restrict__ nd,
                                             float* __restrict__ out) {
    __shared__ __align__(16) float emT[Tq * EMP];     // transposed: emT[j][t] (den: FF values)
    __shared__ __align__(16) unsigned char hist8[Sq * Tq];
    __shared__ int srcl[Sq];
    __shared__ int labl[Sq];
    __shared__ __align__(8) unsigned char predi8[Sq];

    const int lane = threadIdx.x;
    const int b = blockIdx.x & 63;
    const bool vit = blockIdx.x >= 64;

    #pragma unroll
    for (int k = 0; k < 8; ++k) {
        int t = lane + (k << 6);
        srcl[t] = src[b * Sq + t];
        labl[t] = label[b * Sq + t];
    }
    __syncthreads();
    // gather emissions transposed; den path stores FF = exp(em)/16 directly
    if (!vit) {
        #pragma unroll 4
        for (int k = 0; k < 128; ++k) {
            int idx = lane + (k << 6);
            int t = idx >> 4, jj = idx & 15;
            emT[jj * EMP + t] = __expf(table[(size_t)srcl[t] * Tq + jj]) * 0.0625f;
        }
    } else {
        #pragma unroll 4
        for (int k = 0; k < 128; ++k) {
            int idx = lane + (k << 6);
            int t = idx >> 4, jj = idx & 15;
            emT[jj * EMP + t] = table[(size_t)srcl[t] * Tq + jj];
        }
    }
    __syncthreads();

    const int j = lane >> 2;
    const int g = lane & 3;
    const float4* emrow = reinterpret_cast<const float4*>(&emT[j * EMP]);

    // probe the permlane gather network; fall back to bpermute if wrong
    const bool swA = (((lane >> 5) ^ (lane >> 1)) & 1) != 0;
    const bool swB = (((lane >> 4) ^ lane) & 1) != 0;
    int k0 = 0, k1 = 1, k2 = 2, k3 = 3;
    bool fastok = false;
#if HAVE_PL
    {
        u32 q0, q1, q2, q3;
        gather4((u32)j, swA, swB, q0, q1, q2, q3);
        bool ok = ((q0 >> 2) == (u32)g) && ((q1 >> 2) == (u32)g) &&
                  ((q2 >> 2) == (u32)g) && ((q3 >> 2) == (u32)g);
        u32 cov = (1u << (q0 & 3)) | (1u << (q1 & 3)) | (1u << (q2 & 3)) | (1u << (q3 & 3));
        ok = ok && (cov == 15u);
        fastok = (__all(ok ? 1 : 0) != 0);
        if (fastok) { k0 = (int)(q0 & 3); k1 = (int)(q1 & 3); k2 = (int)(q2 & 3); k3 = (int)(q3 & 3); }
    }
#endif
    const int bidx0 = (g << 6), bidx1 = (g << 6) + 16, bidx2 = (g << 6) + 32, bidx3 = (g << 6) + 48;

    if (!vit) {
        // ================= denominator: linear-domain forward (FF precomputed) =================
        float E0 = __expf(trans[(4 * g + k0) * Tq + j]);
        float E1 = __expf(trans[(4 * g + k1) * Tq + j]);
        float E2 = __expf(trans[(4 * g + k2) * Tq + j]);
        float E3 = __expf(trans[(4 * g + k3) * Tq + j]);

        float4 f0 = emrow[0];
        float p = __expf(start_t[j]) * f0.x * 16.0f;   // exp(start + em0)

#define DEN_STEP_PL(ff)  { u32 qa, qb, qc, qd;                                         \
            gather4(__float_as_uint(p), swA, swB, qa, qb, qc, qd);                     \
            float s = (__uint_as_float(qa) * E0 + __uint_as_float(qb) * E1)            \
                    + (__uint_as_float(qc) * E2 + __uint_as_float(qd) * E3);           \
            s += dpp_f<QX1>(s);  s += dpp_f<QX2>(s);  p = s * (ff); }
#define DEN_STEP_BP(ff)  { float p0 = bperm_f(p, bidx0), p1 = bperm_f(p, bidx1),       \
                                 p2 = bperm_f(p, bidx2), p3 = bperm_f(p, bidx3);       \
            float s = (p0 * E0 + p1 * E1) + (p2 * E2 + p3 * E3);                       \
            s += dpp_f<QX1>(s);  s += dpp_f<QX2>(s);  p = s * (ff); }

#if HAVE_PL
        if (fastok) {
            DEN_STEP_PL(f0.y) DEN_STEP_PL(f0.z) DEN_STEP_PL(f0.w)
            float4 fc = emrow[1];
            for (int t0 = 4; t0 < Sq; t0 += 4) {
                float4 fn;
                if (t0 + 4 < Sq) fn = emrow[(t0 >> 2) + 1];
                DEN_STEP_PL(fc.x) DEN_STEP_PL(fc.y) DEN_STEP_PL(fc.z) DEN_STEP_PL(fc.w)
                fc = fn;
            }
        } else
#endif
        {
            DEN_STEP_BP(f0.y) DEN_STEP_BP(f0.z) DEN_STEP_BP(f0.w)
            float4 fc = emrow[1];
            for (int t0 = 4; t0 < Sq; t0 += 4) {
                float4 fn;
                if (t0 + 4 < Sq) fn = emrow[(t0 >> 2) + 1];
                DEN_STEP_BP(fc.x) DEN_STEP_BP(fc.y) DEN_STEP_BP(fc.z) DEN_STEP_BP(fc.w)
                fc = fn;
            }
        }
        float val = p * __expf(end_t[j]);
        #pragma unroll
        for (int off = 1; off < 64; off <<= 1) val += __shfl_xor(val, off);
        float den = (float)(511.0 * 2.7725887222397811) + __logf(val * 0.25f);

        // ================= numerator (raw logits from global table) =================
        float numv = 0.0f;
        int sl = 0;
        #pragma unroll
        for (int k = 0; k < 8; ++k) {
            int t = lane + (k << 6);
            int tag = labl[t];
            int m = pmask[b * Sq + t];
            sl += m;
            float emtt = table[(size_t)srcl[t] * Tq + tag];
            if (t == 0) {
                numv += start_t[tag] + emtt;
            } else {
                int tp = labl[t - 1];
                numv += (float)m * (trans[tp * Tq + tag] + emtt);
            }
        }
        #pragma unroll
        for (int off = 1; off < 64; off <<= 1) {
            numv += __shfl_xor(numv, off);
            sl += __shfl_xor(sl, off);
        }
        if (lane == 0) {
            int last = labl[sl - 1];
            nd[b] = (numv + end_t[last]) - den;
        }
    } else {
        // ================= viterbi forward =================
        float T0 = trans[(4 * g + k0) * Tq + j];
        float T1 = trans[(4 * g + k1) * Tq + j];
        float T2 = trans[(4 * g + k2) * Tq + j];
        float T3 = trans[(4 * g + k3) * Tq + j];
        const int i0 = 4 * g + k0, i1 = 4 * g + k1, i2 = 4 * g + k2, i3 = 4 * g + k3;

#define VIT_STEP_PL(emv, th) { u32 qa, qb, qc, qd;                                     \
            gather4(__float_as_uint(sc), swA, swB, qa, qb, qc, qd);                    \
            float v0 = __uint_as_float(qa) + T0, v1 = __uint_as_float(qb) + T1;        \
            float v2 = __uint_as_float(qc) + T2, v3 = __uint_as_float(qd) + T3;        \
            float ml = fmaxf(fmaxf(v0, v1), fmaxf(v2, v3));                            \
            float m1 = fmaxf(ml, dpp_f<QX1>(ml));                                      \
            float mv = fmaxf(m1, dpp_f<QX2>(m1));                                      \
            sc = mv + (emv);                                                           \
            int c0 = (v0 == mv) ? i0 : 99, c1 = (v1 == mv) ? i1 : 99;                  \
            int c2 = (v2 == mv) ? i2 : 99, c3 = (v3 == mv) ? i3 : 99;                  \
            int li = min(min(c0, c1), min(c2, c3));                                    \
            li = min(li, dpp_i<QX1>(li));  li = min(li, dpp_i<QX2>(li));               \
            if (g == 0) hist8[(th) * Tq + j] = (unsigned char)li; }
#define VIT_STEP_BP(emv, th) { float v0 = bperm_f(sc, bidx0) + T0,                     \
                 v1 = bperm_f(sc, bidx1) + T1, v2 = bperm_f(sc, bidx2) + T2,           \
                 v3 = bperm_f(sc, bidx3) + T3;                                         \
            float ml = fmaxf(fmaxf(v0, v1), fmaxf(v2, v3));                            \
            float m1 = fmaxf(ml, dpp_f<QX1>(ml));                                      \
            float mv = fmaxf(m1, dpp_f<QX2>(m1));                                      \
            sc = mv + (emv);                                                           \
            int c0 = (v0 == mv) ? i0 : 99, c1 = (v1 == mv) ? i1 : 99;                  \
            int c2 = (v2 == mv) ? i2 : 99, c3 = (v3 == mv) ? i3 : 99;                  \
            int li = min(min(c0, c1), min(c2, c3));                                    \
            li = min(li, dpp_i<QX1>(li));  li = min(li, dpp_i<QX2>(li));               \
            if (g == 0) hist8[(th) * Tq + j] = (unsigned char)li; }

        float4 e0 = emrow[0];
        float sc = start_t[j] + e0.x;
#if HAVE_PL
        if (fastok) {
            VIT_STEP_PL(e0.y, 0) VIT_STEP_PL(e0.z, 1) VIT_STEP_PL(e0.w, 2)
            float4 fc = emrow[1];
            for (int t0 = 4; t0 < Sq; t0 += 4) {
                float4 fn;
                if (t0 + 4 < Sq) fn = emrow[(t0 >> 2) + 1];
                VIT_STEP_PL(fc.x, t0 - 1) VIT_STEP_PL(fc.y, t0)
                VIT_STEP_PL(fc.z, t0 + 1) VIT_STEP_PL(fc.w, t0 + 2)
                fc = fn;
            }
        } else
#endif
        {
            VIT_STEP_BP(e0.y, 0) VIT_STEP_BP(e0.z, 1) VIT_STEP_BP(e0.w, 2)
            float4 fc = emrow[1];
            for (int t0 = 4; t0 < Sq; t0 += 4) {
                float4 fn;
                if (t0 + 4 < Sq) fn = emrow[(t0 >> 2) + 1];
                VIT_STEP_BP(fc.x, t0 - 1) VIT_STEP_BP(fc.y, t0)
                VIT_STEP_BP(fc.z, t0 + 1) VIT_STEP_BP(fc.w, t0 + 2)
                fc = fn;
            }
        }
        // final argmax over states (ties -> lowest index)
        float fv = sc + end_t[j];
        int fi = j;
        #pragma unroll
        for (int off = 4; off < 64; off <<= 1) {
            float ov = __shfl_xor(fv, off);
            int oi = __shfl_xor(fi, off);
            bool take = (ov > fv) || (ov == fv && oi < fi);
            fv = take ? ov : fv;
            fi = take ? oi : fi;
        }
        if (lane < 16) hist8[511 * Tq + lane] = (unsigned char)lane;  // identity row
        __syncthreads();

        // ===== backtrack via exact function-composition scan =====
        u64 rp[8];
        #pragma unroll
        for (int k = 0; k < 8; ++k) {
            uint4 rw = *reinterpret_cast<const uint4*>(&hist8[(lane * 8 + k) * Tq]);
            u32 lo = packnib(rw.x) | (packnib(rw.y) << 16);
            u32 hi = packnib(rw.z) | (packnib(rw.w) << 16);
            rp[k] = (u64)lo | ((u64)hi << 32);
        }
        u64 F = rp[7];
        #pragma unroll
        for (int k = 6; k >= 0; --k) {
            u64 nf = 0;
            #pragma unroll
            for (int e = 0; e < 16; ++e) {
                u32 s = (u32)(F >> (e * 4)) & 15u;
                nf |= ((u64)nib64(rp[k], s)) << (e * 4);
            }
            F = nf;
        }
        u32 Flo = (u32)F, Fhi = (u32)(F >> 32);

        u32 pk[8] = {0, 0, 0, 0, 0, 0, 0, 0};
        u32 E = (u32)fi;
        #pragma unroll 64
        for (int c = 63; c >= 0; --c) {
            u64 Fc = ((u64)(u32)__builtin_amdgcn_readlane((int)Fhi, c) << 32)
                   | (u64)(u32)__builtin_amdgcn_readlane((int)Flo, c);
            pk[c >> 3] |= E << ((c & 7) * 4);
            E = nib64(Fc, E);
        }

        u32 a0 = (lane & 8) ? pk[1] : pk[0];
        u32 a1 = (lane & 8) ? pk[3] : pk[2];
        u32 a2 = (lane & 8) ? pk[5] : pk[4];
        u32 a3 = (lane & 8) ? pk[7] : pk[6];
        u32 b0 = (lane & 16) ? a1 : a0;
        u32 b1 = (lane & 16) ? a3 : a2;
        u32 c0s = (lane & 32) ? b1 : b0;
        u32 cur = (c0s >> ((lane & 7) * 4)) & 15u;
        u32 w0 = 0, w1 = 0;
        #pragma unroll
        for (int k = 7; k >= 0; --k) {
            cur = nib64(rp[k], cur);
            if (k >= 4) w1 |= cur << ((k - 4) * 8);
            else        w0 |= cur << (k * 8);
        }
        *reinterpret_cast<uint2*>(&predi8[lane * 8]) = make_uint2(w0, w1);
        __syncthreads();

        // ================= outputs =================
        int cnt = 0;
        #pragma unroll
        for (int k = 0; k < 8; ++k) {
            int s_ = lane + (k << 6);
            int lab = labl[s_];
            int pr = (int)predi8[s_];
            int mpr = lab > 0 ? pr : 0;
            out[2 + b * Sq + s_] = (float)mpr;
            out[2 + Bq * Sq + b * Sq + s_] = (float)lab;
            cnt += (mpr == lab) ? 1 : 0;
        }
        #pragma unroll
        for (int off = 1; off < 64; off <<= 1) cnt += __shfl_xor(cnt, off);
        if (lane == 0) atomicAdd(out + 1, (float)cnt);
    }
}

// ---------- K2: loss = -(sum_b nd[b]) / B ----------
__global__ __launch_bounds__(64) void k_final(const float* __restrict__ nd,
                                              float* __restrict__ out) {
    float v = nd[threadIdx.x];
    #pragma unroll
    for (int off = 1; off < 64; off <<= 1) v += __shfl_xor(v, off);
    if (threadIdx.x == 0) out[0] = -v * (1.0f / (float)Bq);
}

extern "C" void kernel_launch(void* const* d_in, const int* in_sizes, int n_in,
                              void* d_out, int out_size, void* d_ws, size_t ws_size,
                              hipStream_t stream) {
    const int*   src   = (const int*)d_in[0];
    const int*   label = (const int*)d_in[1];
    const int*   pmask = (const int*)d_in[2];
    const float* emb   = (const float*)d_in[3];
    const float* W     = (const float*)d_in[4];
    const float* bias  = (const float*)d_in[5];
    const float* st    = (const float*)d_in[6];
    const float* en    = (const float*)d_in[7];
    const float* tr    = (const float*)d_in[8];
    float* out = (float*)d_out;

    float* table = (float*)d_ws;
    float* nd    = table + (size_t)Vq * Tq;

    const int nblk = (Vq + 63) / 64;   // 477
    k_table<<<nblk, 256, 0, stream>>>(emb, W, bias, table, out);
    k_scan<<<128, 64, 0, stream>>>(src, label, pmask, table, st, en, tr, nd, out);
    k_final<<<1, 64, 0, stream>>>(nd, out);
}